// Round 3
// baseline (268.163 us; speedup 1.0000x reference)
//
#include <hip/hip_runtime.h>

// Problem constants (from reference):
//   N = 64 (protein length), B = 32 (batch), L = 2N-1 = 127 (lattice side)
//   out = (B, L, L, L) float32 = 65,548,256 elems = 262,193,024 B (~262 MB)
//
// R3: single fused kernel. The harness poison fill (1.049 GB, ~160us) is an
// untouchable floor inside the timed window; the controllable slice is the
// 262 MB zero + 2048-point scatter. R2's memset+scatter slice was ~63us
// (memset picks a ~5 TB/s config at 262 MB + dispatch gap). Here each block
// owns a contiguous chunk, finds the (avg 1-2) scatter points landing in it
// via a cooperative scan into an LDS list, then does ONE plain coalesced
// float4 write pass composing zero+scatter per cell. Every cell written
// exactly once with its final value: no global atomics, no ordering hazard,
// no second dispatch. Plain stores (R1 lesson: nt bypasses L2 write-combining
// and regressed 20%).
//
// Floor: poison ~160 + 262MB @ ~6.3 TB/s ~= 42 + eps => ~205us total.

constexpr int PN = 64;
constexpr int PB = 32;
constexpr int PL = 2 * PN - 1;                                 // 127
constexpr long long TOTAL_F = (long long)PB * PL * PL * PL;    // 65,548,256
constexpr long long TOTAL_V4 = TOTAL_F / 4;                    // 16,387,064
constexpr int NPTS = PB * PN;                                  // 2048

constexpr int FB = 256;                                        // block size
constexpr int FGRID = 2048;                                    // 8 blocks/CU
constexpr int CH = (int)((TOTAL_V4 + FGRID - 1) / FGRID);      // 8002 float4/block

typedef float v4f __attribute__((ext_vector_type(4)));

__global__ __launch_bounds__(FB) void lattice_fused_kernel(
        const float* __restrict__ acids,
        const int*   __restrict__ idx,
        const int*   __restrict__ mask,
        v4f*         __restrict__ out) {
    __shared__ int   s_cnt;
    __shared__ int   s_off[NPTS];   // element offsets of points in this chunk
    __shared__ float s_val[NPTS];

    const int tid = threadIdx.x;
    const long long lo = (long long)blockIdx.x * CH;           // first float4
    long long hi = lo + CH;
    if (hi > TOTAL_V4) hi = TOTAL_V4;
    if (tid == 0) s_cnt = 0;
    __syncthreads();

    // Stage 1: cooperative scan of all 2048 scatter points; keep those whose
    // target cell lies in this block's chunk (avg 1, LDS sized for worst 2048).
    const long long elo = lo * 4, ehi = hi * 4;
    for (int p = tid; p < NPTS; p += FB) {
        if (mask[p] != 0) {
            long long b  = p >> 6;                             // p / N
            long long i0 = idx[3 * p + 0] + (PN - 1);
            long long i1 = idx[3 * p + 1] + (PN - 1);
            long long i2 = idx[3 * p + 2] + (PN - 1);
            long long off = ((b * PL + i0) * PL + i1) * PL + i2;
            if (off >= elo && off < ehi) {
                int slot = atomicAdd(&s_cnt, 1);               // LDS atomic
                s_off[slot] = (int)off;
                s_val[slot] = acids[p];
            }
        }
    }
    __syncthreads();
    const int n = s_cnt;

    // Stage 2: single coalesced write pass — each float4 written exactly once
    // with its final value (zero + summed scatter hits). No global atomics.
    if (n == 0) {                                              // block-uniform fast path
        const v4f z = {0.f, 0.f, 0.f, 0.f};
        for (long long t = lo + tid; t < hi; t += FB)
            out[t] = z;
    } else {
        for (long long t = lo + tid; t < hi; t += FB) {
            v4f z = {0.f, 0.f, 0.f, 0.f};
            const int e0 = (int)(t << 2);
            for (int k = 0; k < n; ++k) {                      // n is ~1-2
                int d = s_off[k] - e0;                         // LDS broadcast read
                if ((unsigned)d < 4u) {
                    float v = s_val[k];
                    if      (d == 0) z.x += v;                 // static component
                    else if (d == 1) z.y += v;                 // update (no dynamic
                    else if (d == 2) z.z += v;                 // vector indexing ->
                    else             z.w += v;                 // no scratch)
                }
            }
            out[t] = z;
        }
    }
}

extern "C" void kernel_launch(void* const* d_in, const int* in_sizes, int n_in,
                              void* d_out, int out_size, void* d_ws, size_t ws_size,
                              hipStream_t stream) {
    const float* acids = (const float*)d_in[0];   // (B,N) f32
    const int*   idx   = (const int*)  d_in[1];   // (B,N,3) i32
    const int*   mask  = (const int*)  d_in[2];   // (B,N) bool -> i32 per harness
    float* out = (float*)d_out;

    lattice_fused_kernel<<<FGRID, FB, 0, stream>>>(acids, idx, mask, (v4f*)out);
}

// Round 4
// 260.939 us; speedup vs baseline: 1.0277x; 1.0277x over previous
//
#include <hip/hip_runtime.h>

// Problem constants (from reference):
//   N = 64 (protein length), B = 32 (batch), L = 2N-1 = 127 (lattice side)
//   out = (B, L, L, L) float32 = 65,548,256 elems = 262,193,024 B (~262 MB)
//
// R4 HW model (from R0/R1/R3 evidence): write BW on MI355X is governed by the
// number of concurrent write streams (HBM row locality), not thread count.
//   - rocclr fill: ~210 persistent wgs, sequential per-wg streams -> 6.5 TB/s
//     at 10% occupancy (the poison fills prove this every run).
//   - R0 one-shot 64k blocks (narrow live window): 3.6 TB/s.
//   - R1/R3 grid-stride with 2048-8192 resident streams: 2.6 TB/s (nt was NOT
//     the culprit in R1 -- R3 reproduced the slowdown with plain stores).
// Fix: mimic the fill's shape. 256 blocks (1/CU, 4 waves), each owns ONE
// contiguous ~1MB chunk, walked block-strided so the block's 4 waves advance
// through a ~4KB sequential window => 256 sequential write streams chip-wide.
//
// Fusion kept, but out of the hot loop: stage1 scan 2048 pts -> LDS list of
// this chunk's hits (~6 expected); stage2 PURE zero pass (no per-float4
// checks); stage3 after __syncthreads() (drains vmcnt(0) -> zeros complete)
// apply hits via global atomicAdd. Points partition uniquely by chunk -> no
// cross-block hazard; same-address order guaranteed by the barrier drain.
//
// Floor: poison ~160 (harness, untouchable) + 262MB @ ~6 TB/s ~= 44 + eps.

constexpr int PN = 64;
constexpr int PB = 32;
constexpr int PL = 2 * PN - 1;                                 // 127
constexpr long long TOTAL_F = (long long)PB * PL * PL * PL;    // 65,548,256
constexpr long long TOTAL_V4 = TOTAL_F / 4;                    // 16,387,064
constexpr int NPTS = PB * PN;                                  // 2048

constexpr int ZB = 256;                                        // 4 waves/block
constexpr int ZGRID = 256;                                     // 1 block/CU
constexpr int CH = (int)((TOTAL_V4 + ZGRID - 1) / ZGRID);      // 64,012 float4s (~1MB)

typedef float v4f __attribute__((ext_vector_type(4)));

__global__ __launch_bounds__(ZB) void lattice_fused_kernel(
        const float* __restrict__ acids,
        const int*   __restrict__ idx,
        const int*   __restrict__ mask,
        float*       __restrict__ outf) {
    __shared__ int   s_cnt;
    __shared__ int   s_off[NPTS];   // element offsets of hits in this chunk
    __shared__ float s_val[NPTS];

    v4f* __restrict__ out = (v4f*)outf;
    const int tid = threadIdx.x;
    const long long lo = (long long)blockIdx.x * CH;           // first float4
    long long hi = lo + CH;
    if (hi > TOTAL_V4) hi = TOTAL_V4;
    if (tid == 0) s_cnt = 0;
    __syncthreads();

    // Stage 1: scan all 2048 scatter points; keep those landing in this chunk.
    // (40KB of input x 256 blocks = 10MB of L2/L3-absorbed reads; negligible.)
    const long long elo = lo * 4, ehi = hi * 4;
    for (int p = tid; p < NPTS; p += ZB) {
        if (mask[p] != 0) {
            long long b  = (long long)(p >> 6);                // p / N
            long long i0 = idx[3 * p + 0] + (PN - 1);
            long long i1 = idx[3 * p + 1] + (PN - 1);
            long long i2 = idx[3 * p + 2] + (PN - 1);
            long long off = ((b * PL + i0) * PL + i1) * PL + i2;
            if (off >= elo && off < ehi) {
                int slot = atomicAdd(&s_cnt, 1);               // LDS atomic
                s_off[slot] = (int)off;                        // fits: < 2^26
                s_val[slot] = acids[p];
            }
        }
    }

    // Stage 2: pure zero pass. Block-strided: all 4 waves advance together
    // through a 4KB sequential window of the block's contiguous 1MB chunk.
    const v4f z = {0.f, 0.f, 0.f, 0.f};
    for (long long t = lo + tid; t < hi; t += ZB) {
        out[t] = z;
    }

    // Stage 3: barrier drains vmcnt(0) -> all zeros of this chunk complete
    // and stage-1 list visible. Apply the ~6 hits (worst case 2048) with
    // device-scope atomics (handles index collisions).
    __syncthreads();
    const int n = s_cnt;
    for (int k = tid; k < n; k += ZB) {
        atomicAdd(outf + s_off[k], s_val[k]);
    }
}

extern "C" void kernel_launch(void* const* d_in, const int* in_sizes, int n_in,
                              void* d_out, int out_size, void* d_ws, size_t ws_size,
                              hipStream_t stream) {
    const float* acids = (const float*)d_in[0];   // (B,N) f32
    const int*   idx   = (const int*)  d_in[1];   // (B,N,3) i32
    const int*   mask  = (const int*)  d_in[2];   // (B,N) bool -> i32 per harness
    float* out = (float*)d_out;

    lattice_fused_kernel<<<ZGRID, ZB, 0, stream>>>(acids, idx, mask, out);
}